// Round 5
// baseline (1056.520 us; speedup 1.0000x reference)
//
#include <hip/hip_runtime.h>
#include <cstdint>
#include <cstddef>

// Round 8 (= round 7 resubmitted; round-7 bench died on container acquire, no
// kernel signal). (a) kg_bmm template-split: <1> fat step-0 (f32 read + early
// gB write-through), <0> lean bf16-only steps 1-4 (round-3 regression was the
// fat kernel taxing every step: VGPR 68, occ 21%). (b) kg_pre rewritten as
// bf16 MFMA with hi/lo compensation (x=hi+lo, W=wh+wl, 3 MFMAs: f32-grade
// product) - pre was ~60us/step of f32 VALU.
// B=8, SL=1024, D=128, E=4, STEPS=5.

typedef unsigned short u16;
typedef unsigned int u32;
typedef float f32x4 __attribute__((ext_vector_type(4)));
typedef short short8 __attribute__((ext_vector_type(8)));   // 8 bf16 (4 VGPRs)
typedef u16 u16x4 __attribute__((ext_vector_type(4)));
typedef u16 u16x8 __attribute__((ext_vector_type(8)));

__device__ __forceinline__ float b2f(u16 h) {
  union { u32 u; float f; } v; v.u = ((u32)h) << 16; return v.f;
}
__device__ __forceinline__ u16 f2bf(float f) {
  union { float f; u32 u; } v; v.f = f;
  u32 r = (v.u + 0x7fffu + ((v.u >> 16) & 1u)) >> 16;
  return (u16)r;
}
__device__ __forceinline__ float ldu(const void* p, size_t i, int flag) {
  return flag ? ((const float*)p)[i] : b2f(((const u16*)p)[i]);
}
// async global->LDS, 16B per lane, dest = wave-uniform base + lane*16
__device__ __forceinline__ void gload_lds16(const void* g, void* l) {
  __builtin_amdgcn_global_load_lds((const __attribute__((address_space(1))) void*)g,
                                   (__attribute__((address_space(3))) void*)l,
                                   16, 0, 0);
}

// ---- detect input dtype from batchgraphin bit patterns.
__global__ void k_detect(const u16* g, int* flag) {
  __shared__ int bad;
  if (threadIdx.x == 0) bad = 0;
  __syncthreads();
  int any = 0;
  for (int i = threadIdx.x; i < 8192; i += 256) any |= (g[i] > 0x3B00);
  if (any) atomicOr(&bad, 1);
  __syncthreads();
  if (threadIdx.x == 0) *flag = bad;   // 1 => inputs are f32
}

// ---- generic convert-to-f32
__global__ void k_cvtf(const void* src, float* dst, int n, const int* flagp) {
  int i = blockIdx.x * 256 + threadIdx.x;
  if (i < n) dst[i] = ldu(src, i, *flagp);
}

// ---- Weff = sum_e Wcat[:, e*128+k], stored j-major as bf16 hi/lo pair.
// weffHT/weffLT: [j=0..1023][k=0..127]. biasf = [b_in | b_out] f32.
__global__ void k_weff(const void* Win, const void* bin, const void* Wout, const void* bout,
                       u16* weffHT, u16* weffLT, float* biasf, const int* flagp) {
  int flag = *flagp;
  int idx = blockIdx.x * 256 + threadIdx.x;   // 131072
  int j = idx >> 7, k = idx & 127;
  float s = 0.f;
  if (j < 512) {
#pragma unroll
    for (int e = 0; e < 4; e++) s += ldu(Win, (size_t)j * 512 + e * 128 + k, flag);
  } else {
#pragma unroll
    for (int e = 0; e < 4; e++) s += ldu(Wout, (size_t)(j - 512) * 512 + e * 128 + k, flag);
  }
  u16 h = f2bf(s);
  weffHT[(size_t)j * 128 + k] = h;
  weffLT[(size_t)j * 128 + k] = f2bf(s - b2f(h));
  if (idx < 1024) biasf[idx] = (idx < 512) ? ldu(bin, idx, flag) : ldu(bout, idx - 512, flag);
}

// ---- WT[k][n] = W[n][k] for the 128x384 gate weights
__global__ void k_wt(const void* W, const void* bv, float* WT, float* bf, const int* flagp) {
  int flag = *flagp;
  int idx = blockIdx.x * 256 + threadIdx.x;   // 49152
  int n = idx / 384, k = idx % 384;
  WT[k * 128 + n] = ldu(W, idx, flag);
  if (idx < 128) bf[idx] = ldu(bv, idx, flag);
}

// ---- MFMA pre: per (b, 32-s block): Y[32,1024] = X[32,128] @ WeffT^T, hi/lo
// compensated (err ~2^-18). Epilogue transposes through LDS so gpreT rows get
// contiguous 256B stores. gpreT[gb][d][k2=s*4+e] = bf16(Y[s][gate*512+e*128+d]+bias).
__global__ __launch_bounds__(512, 2) void kg_pre_mfma(
    const u16* __restrict__ weffHT, const u16* __restrict__ weffLT,
    const float* __restrict__ biasf, const float* __restrict__ outF,
    u16* __restrict__ gpreT) {
  __shared__ __align__(16) u16 AH[32 * 128];
  __shared__ __align__(16) u16 AL[32 * 128];
  __shared__ __align__(16) u16 ybuf[32 * 1024];
  int t = threadIdx.x;
  int b = blockIdx.y;
  int s0 = blockIdx.x * 32;
  {  // stage A: 32 rows x 128 k f32 -> hi/lo bf16, XOR-swizzled
    int row = t >> 4, c8 = (t & 15) * 8;
    const float* src = outF + (((size_t)(b * 1024 + s0 + row)) << 7) + c8;
    f32x4 x0 = *(const f32x4*)src;
    f32x4 x1 = *(const f32x4*)(src + 4);
    u16x8 vh, vl;
#pragma unroll
    for (int i = 0; i < 4; i++) {
      float x = x0[i]; u16 h = f2bf(x);
      vh[i] = h; vl[i] = f2bf(x - b2f(h));
      x = x1[i]; h = f2bf(x);
      vh[i + 4] = h; vl[i + 4] = f2bf(x - b2f(h));
    }
    int bc = (c8 * 2) ^ ((row & 7) << 4);
    *(u16x8*)((char*)AH + row * 256 + bc) = vh;
    *(u16x8*)((char*)AL + row * 256 + bc) = vl;
  }
  __syncthreads();
  int lane = t & 63, w = t >> 6;
  int wm = w >> 2, wn = w & 3;        // wave tile: 16 s x 256 j
  int lr = lane & 15, lk = lane >> 4;
  int n0 = wn * 256;
  int arow = wm * 16 + lr;
  int abase_row = arow * 256;
  int aswz = (arow & 7) << 4;
  f32x4 acc[16] = {};
#pragma unroll
  for (int kk = 0; kk < 4; kk++) {
    int kb = (kk * 64 + lk * 16) ^ aswz;
    short8 ah = *(const short8*)((const char*)AH + abase_row + kb);
    short8 al = *(const short8*)((const char*)AL + abase_row + kb);
    int wko = kk * 64 + lk * 16;      // byte offset within a 256B W row
#pragma unroll
    for (int nf = 0; nf < 16; nf++) {
      int j = n0 + nf * 16 + lr;
      short8 wh = *(const short8*)((const char*)weffHT + (size_t)j * 256 + wko);
      short8 wl = *(const short8*)((const char*)weffLT + (size_t)j * 256 + wko);
      acc[nf] = __builtin_amdgcn_mfma_f32_16x16x32_bf16(ah, wh, acc[nf], 0, 0, 0);
      acc[nf] = __builtin_amdgcn_mfma_f32_16x16x32_bf16(ah, wl, acc[nf], 0, 0, 0);
      acc[nf] = __builtin_amdgcn_mfma_f32_16x16x32_bf16(al, wh, acc[nf], 0, 0, 0);
    }
  }
  // dump acc (+bias, round to bf16) into ybuf[s][j]
#pragma unroll
  for (int nf = 0; nf < 16; nf++) {
    int j = n0 + nf * 16 + lr;
    float bj = biasf[j];
#pragma unroll
    for (int i = 0; i < 4; i++) {
      int s = wm * 16 + lk * 4 + i;   // C/D: col=lane&15, row=(lane>>4)*4+reg
      ybuf[s * 1024 + j] = f2bf(acc[nf][i] + bj);
    }
  }
  __syncthreads();
  // output: 256 rows (gate*128+d), each gets 128 contiguous k2 = s*4+e
#pragma unroll
  for (int p = 0; p < 8; p++) {
    int row = p * 32 + (t >> 4);
    int gate = row >> 7, d = row & 127;
    int c = (t & 15) * 8;
    u16x8 v;
#pragma unroll
    for (int i = 0; i < 8; i++) {
      int k2 = c + i;
      v[i] = ybuf[(k2 >> 2) * 1024 + gate * 512 + (k2 & 3) * 128 + d];
    }
    *(u16x8*)(gpreT + (((size_t)((gate * 8 + b) * 128 + d)) << 12) + (size_t)s0 * 4 + c) = v;
  }
}

// ---- MFMA bmm: per (gate,b,khalf): Cpart[1024,128] += graph[1024,2048]·gpre[2048,128]
// WMODE=1: fat (f32-capable; converts + writes gB immediately after load).
// WMODE=0: lean bf16-only (steps 1-4 when workspace cache is valid).
template <int WMODE>
__global__ __launch_bounds__(256, 2) void kg_bmm(
    const void* __restrict__ gin, const void* __restrict__ gout,
    u16* __restrict__ gB, int useGB, int writeStep,
    const u16* __restrict__ gpreT,
    float* __restrict__ P,
    const int* __restrict__ flagp) {
  __shared__ __align__(16) u16 bufA[2][4096];   // [64 s-rows][64 k], swizzled
  __shared__ __align__(16) u16 bufB[2][8192];   // [128 d-cols][64 k], swizzled

  int t = threadIdx.x;
  int lin0 = blockIdx.x + (blockIdx.y << 4) + (blockIdx.z << 8);
  int lin = ((lin0 & 7) << 6) + (lin0 >> 3);    // XCD chunk swizzle, 512%8==0
  int mb = lin & 15, gb = (lin >> 4) & 15, kh = lin >> 8;
  int gate = gb >> 3, b = gb & 7;
  int ms0 = mb << 6;
  int kbase = kh << 11;

  int flag = *flagp;
  int doWrite = 0, srcBF = 1;
  const void* Asrc;
  size_t abase;   // element index of A[ms0][kbase] in Asrc
  if (WMODE == 0) {
    if (flag) { Asrc = gB;                abase = (((size_t)(gb * 1024 + ms0)) << 12) + kbase; }
    else      { Asrc = gate ? gout : gin; abase = (((size_t)(b  * 1024 + ms0)) << 12) + kbase; }
  } else {
    doWrite = useGB && flag && writeStep;
    srcBF = (flag == 0);
    Asrc = gate ? gout : gin;
    abase = (((size_t)(b * 1024 + ms0)) << 12) + kbase;
  }
  size_t gwbase = (((size_t)(gb * 1024 + ms0)) << 12) + kbase;   // gB write base

  int arow = t >> 4;            // 0..15 (+16 per it)
  int acolE = (t & 15) << 2;    // elem col
  int acb = (t & 15) << 3;      // byte col
  int aswz = (arow & 7) << 4;
  int lane = t & 63, w = t >> 6;
  int wm = w >> 1, wn = w & 1;
  int lr = lane & 15, lk = lane >> 4;
  int r0 = wm * 32 + lr;
  int c0 = wn * 64 + lr;
  int fswz = (lr & 7) << 4;

  f32x4 acc[2][4] = {};
  u16x4 ah[4];

  auto stageA_load = [&](int st) {
    size_t kk = abase + (size_t)st * 64;
    if (WMODE == 0 || srcBF) {
      const u16* p = (const u16*)Asrc;
#pragma unroll
      for (int it = 0; it < 4; it++)
        ah[it] = *(const u16x4*)(p + kk + (size_t)(arow + it * 16) * 4096 + acolE);
    } else {
      const float* p = (const float*)Asrc;
#pragma unroll
      for (int it = 0; it < 4; it++) {
        const f32x4* a = (const f32x4*)(p + kk + (size_t)(arow + it * 16) * 4096 + acolE);
        f32x4 af = doWrite ? __builtin_nontemporal_load(a) : *a;
        u16x4 v;
        v[0] = f2bf(af[0]); v[1] = f2bf(af[1]); v[2] = f2bf(af[2]); v[3] = f2bf(af[3]);
        ah[it] = v;
        if (doWrite)   // store early: overlaps with stageB + compute
          *(u16x4*)(gB + gwbase + (size_t)st * 64 + (size_t)(arow + it * 16) * 4096 + acolE) = v;
      }
    }
  };
  auto stageA_write = [&](int nb) {
#pragma unroll
    for (int it = 0; it < 4; it++)
      *(u16x4*)((char*)bufA[nb] + (arow + it * 16) * 128 + (acb ^ aswz)) = ah[it];
  };
  auto stageB = [&](int st, int nb) {
    size_t kk = (size_t)kbase + (size_t)st * 64;
#pragma unroll
    for (int c = 0; c < 4; c++) {
      int col = (w << 5) + (c << 3) + (lane >> 3);
      int j = (lane & 7) ^ (col & 7);            // inverse swizzle on source
      const u16* g = gpreT + (((size_t)(gb * 128 + col)) << 12) + kk + (size_t)j * 8;
      u16* l = &bufB[nb][w * 2048 + c * 512];    // wave-uniform dest base
      gload_lds16(g, l);
    }
  };
  auto compute = [&](int cur) {
    const char* A = (const char*)bufA[cur];
    const char* B = (const char*)bufB[cur];
#pragma unroll
    for (int ks = 0; ks < 2; ks++) {
      int kb = (ks * 64 + lk * 16) ^ fswz;
      short8 a0 = *(const short8*)(A + r0 * 128 + kb);
      short8 a1 = *(const short8*)(A + r0 * 128 + 2048 + kb);
#pragma unroll
      for (int nf = 0; nf < 4; nf++) {
        short8 bv = *(const short8*)(B + c0 * 128 + nf * 2048 + kb);
        acc[0][nf] = __builtin_amdgcn_mfma_f32_16x16x32_bf16(a0, bv, acc[0][nf], 0, 0, 0);
        acc[1][nf] = __builtin_amdgcn_mfma_f32_16x16x32_bf16(a1, bv, acc[1][nf], 0, 0, 0);
      }
    }
  };

  stageA_load(0);
  stageB(0, 0);
  stageA_write(0);
  __syncthreads();
  int cur = 0;
#pragma unroll 2
  for (int st = 0; st < 32; st++) {       // 2048 / 64
    if (st < 31) { stageA_load(st + 1); stageB(st + 1, cur ^ 1); }
    compute(cur);
    if (st < 31) stageA_write(cur ^ 1);
    __syncthreads();
    cur ^= 1;
  }

  float* Pp = P + (((size_t)(kh * 16 + gb)) << 17);   // *1024*128
#pragma unroll
  for (int mf = 0; mf < 2; mf++) {
#pragma unroll
    for (int nf = 0; nf < 4; nf++) {
      int rowb = ms0 + wm * 32 + mf * 16 + lk * 4;
      int col = wn * 64 + nf * 16 + lr;
#pragma unroll
      for (int j = 0; j < 4; j++)
        Pp[(size_t)(rowb + j) * 128 + col] = acc[mf][nf][j];
    }
  }
}

// ---- fused gate tail: combine K-split partials + r,z,h gates + state update.
__global__ __launch_bounds__(256, 2) void kg_gate(
    const float* __restrict__ P, float* __restrict__ outF,
    const float* __restrict__ WTr, const float* __restrict__ WTz,
    const float* __restrict__ WTt,
    const float* __restrict__ brf, const float* __restrict__ bzf,
    const float* __restrict__ btf,
    const int* __restrict__ flagp, void* __restrict__ dout, int writeOut) {
  __shared__ __align__(16) float cs[16 * 384];
  __shared__ __align__(16) float rs[16 * 128];
  int t = threadIdx.x;
  int m0 = blockIdx.x * 16;
  int b = m0 >> 10;
  for (int i4 = t; i4 < 1536; i4 += 256) {
    int r = i4 / 96, q = i4 % 96;
    int m = m0 + r, s = m & 1023;
    f32x4 v;
    if (q < 64) {
      int gate = q >> 5;
      size_t idx = (((size_t)(gate * 8 + b)) << 17) + ((size_t)s << 7) + ((size_t)(q & 31) << 2);
      v = *(const f32x4*)(P + idx) + *(const f32x4*)(P + ((size_t)1 << 21) + idx);
    } else {
      v = *(const f32x4*)(outF + ((size_t)m << 7) + ((q - 64) << 2));
    }
    *(f32x4*)&cs[r * 384 + (q << 2)] = v;
  }
  __syncthreads();
  int n = t & 127, mh = t >> 7;
  float accR[8] = {}, accZ[8] = {}, accT[8] = {};
  for (int kq = 0; kq < 64; kq++) {          // K = 0..255: r,z,t
    float wr[4], wz[4], wt[4];
#pragma unroll
    for (int kl = 0; kl < 4; kl++) {
      wr[kl] = WTr[(kq * 4 + kl) * 128 + n];
      wz[kl] = WTz[(kq * 4 + kl) * 128 + n];
      wt[kl] = WTt[(kq * 4 + kl) * 128 + n];
    }
#pragma unroll
    for (int mi = 0; mi < 8; mi++) {
      f32x4 c = *(const f32x4*)&cs[(mh * 8 + mi) * 384 + kq * 4];
#pragma unroll
      for (int kl = 0; kl < 4; kl++) {
        accR[mi] += c[kl] * wr[kl];
        accZ[mi] += c[kl] * wz[kl];
        accT[mi] += c[kl] * wt[kl];
      }
    }
  }
  for (int kq = 64; kq < 96; kq++) {         // K = 256..383: r,z only (out slice)
    float wr[4], wz[4];
#pragma unroll
    for (int kl = 0; kl < 4; kl++) {
      wr[kl] = WTr[(kq * 4 + kl) * 128 + n];
      wz[kl] = WTz[(kq * 4 + kl) * 128 + n];
    }
#pragma unroll
    for (int mi = 0; mi < 8; mi++) {
      f32x4 c = *(const f32x4*)&cs[(mh * 8 + mi) * 384 + kq * 4];
#pragma unroll
      for (int kl = 0; kl < 4; kl++) {
        accR[mi] += c[kl] * wr[kl];
        accZ[mi] += c[kl] * wz[kl];
      }
    }
  }
  float bR = brf[n], bZ = bzf[n], bT = btf[n];
  float z8[8];
#pragma unroll
  for (int mi = 0; mi < 8; mi++) {
    int row = mh * 8 + mi;
    float r = 1.f / (1.f + __expf(-(accR[mi] + bR)));
    z8[mi] = 1.f / (1.f + __expf(-(accZ[mi] + bZ)));
    rs[row * 128 + n] = r * cs[row * 384 + 256 + n];
  }
  __syncthreads();
  for (int kq = 0; kq < 32; kq++) {          // t-gate tail: (r*out) @ WTt[256:]
    float wt[4];
#pragma unroll
    for (int kl = 0; kl < 4; kl++) wt[kl] = WTt[(256 + kq * 4 + kl) * 128 + n];
#pragma unroll
    for (int mi = 0; mi < 8; mi++) {
      f32x4 c = *(const f32x4*)&rs[(mh * 8 + mi) * 128 + kq * 4];
#pragma unroll
      for (int kl = 0; kl < 4; kl++) accT[mi] += c[kl] * wt[kl];
    }
  }
  int flag = *flagp;
#pragma unroll
  for (int mi = 0; mi < 8; mi++) {
    int row = mh * 8 + mi;
    int m = m0 + row;
    size_t o = (size_t)m * 128 + n;
    float h = tanhf(accT[mi] + bT);
    float z = z8[mi];
    float ov = cs[row * 384 + 256 + n];
    float res = (1.f - z) * ov + z * h;
    outF[o] = res;
    if (writeOut) {
      if (flag) ((float*)dout)[o] = res;
      else      ((u16*)dout)[o] = f2bf(res);
    }
  }
}

extern "C" void kernel_launch(void* const* d_in, const int* in_sizes, int n_in,
                              void* d_out, int out_size, void* d_ws, size_t ws_size,
                              hipStream_t stream) {
  const void* X    = d_in[0];
  const void* Gin  = d_in[1];
  const void* Gout = d_in[2];
  const void* Win  = d_in[3];
  const void* bin  = d_in[4];
  const void* Wout = d_in[5];
  const void* bout = d_in[6];
  const void* Wr   = d_in[7];
  const void* br   = d_in[8];
  const void* Wz   = d_in[9];
  const void* bz   = d_in[10];
  const void* Wt   = d_in[11];
  const void* bt   = d_in[12];

  char* w = (char*)d_ws;
  auto alloc = [&](size_t n) { char* p = w; w += (n + 255) & ~(size_t)255; return p; };
  int*   flag    = (int*)alloc(4);
  u16*   weffHT  = (u16*)alloc((size_t)1024 * 128 * 2);              // 256 KB
  u16*   weffLT  = (u16*)alloc((size_t)1024 * 128 * 2);              // 256 KB
  float* biasf   = (float*)alloc(1024 * 4);
  float* WTr     = (float*)alloc((size_t)384 * 128 * 4);
  float* WTz     = (float*)alloc((size_t)384 * 128 * 4);
  float* WTt     = (float*)alloc((size_t)384 * 128 * 4);
  float* brf     = (float*)alloc(128 * 4);
  float* bzf     = (float*)alloc(128 * 4);
  float* btf     = (float*)alloc(128 * 4);
  float* outF    = (float*)alloc((size_t)8192 * 128 * 4);            // 4 MB
  u16*   gpreT   = (u16*)alloc((size_t)16 * 128 * 4096 * 2);         // 16 MB bf16 [gb][d][k]
  float* partial = (float*)alloc((size_t)2 * 16 * 1024 * 128 * 4);   // 16 MB K-split partials
  u16*   gB      = (u16*)alloc((size_t)2 * 8 * 1024 * 4096 * 2);     // 128 MB bf16 graph
  int wsok = ((size_t)(w - (char*)d_ws) <= ws_size) ? 1 : 0;
  (void)in_sizes; (void)n_in; (void)out_size;

  k_detect<<<1, 256, 0, stream>>>((const u16*)Gin, flag);
  k_weff<<<512, 256, 0, stream>>>(Win, bin, Wout, bout, weffHT, weffLT, biasf, flag);
  k_wt<<<192, 256, 0, stream>>>(Wr, br, WTr, brf, flag);
  k_wt<<<192, 256, 0, stream>>>(Wz, bz, WTz, bzf, flag);
  k_wt<<<192, 256, 0, stream>>>(Wt, bt, WTt, btf, flag);
  k_cvtf<<<4096, 256, 0, stream>>>(X, outF, 1048576, flag);

  for (int step = 0; step < 5; step++) {
    kg_pre_mfma<<<dim3(32, 8), 512, 0, stream>>>(weffHT, weffLT, biasf, outF, gpreT);
    if (step == 0 || !wsok)
      kg_bmm<1><<<dim3(16, 16, 2), 256, 0, stream>>>(Gin, Gout, gB, wsok,
                                                     (step == 0) ? 1 : 0,
                                                     gpreT, partial, flag);
    else
      kg_bmm<0><<<dim3(16, 16, 2), 256, 0, stream>>>(Gin, Gout, gB, wsok, 0,
                                                     gpreT, partial, flag);
    kg_gate<<<512, 256, 0, stream>>>(partial, outF, WTr, WTz, WTt, brf, bzf, btf,
                                     flag, d_out, (step == 4) ? 1 : 0);
  }
}

// Round 7
// 892.358 us; speedup vs baseline: 1.1840x; 1.1840x over previous
//
#include <hip/hip_runtime.h>
#include <cstdint>
#include <cstddef>

// Round 10 (= round 9 resubmitted; round-9 bench died on container acquire
// twice, no kernel signal — same infra failure as round 7, whose identical
// resubmit then passed). (a) kg_bmm<1> gB store back at stageA_write placement
// (round-3 measured 134us; round-5's early-store = 174us: the store's
// vmcnt-wait blocked stageB prefetch issue). (b) kg_gate -> MFMA with hi/lo
// compensation on both operands (err ~2^-18, f32-grade): gate tail was
// ~70us/step of f32 VALU, largest remaining pool (~350us).
// B=8, SL=1024, D=128, E=4, STEPS=5.

typedef unsigned short u16;
typedef unsigned int u32;
typedef float f32x4 __attribute__((ext_vector_type(4)));
typedef short short8 __attribute__((ext_vector_type(8)));   // 8 bf16 (4 VGPRs)
typedef u16 u16x4 __attribute__((ext_vector_type(4)));
typedef u16 u16x8 __attribute__((ext_vector_type(8)));

__device__ __forceinline__ float b2f(u16 h) {
  union { u32 u; float f; } v; v.u = ((u32)h) << 16; return v.f;
}
__device__ __forceinline__ u16 f2bf(float f) {
  union { float f; u32 u; } v; v.f = f;
  u32 r = (v.u + 0x7fffu + ((v.u >> 16) & 1u)) >> 16;
  return (u16)r;
}
__device__ __forceinline__ float ldu(const void* p, size_t i, int flag) {
  return flag ? ((const float*)p)[i] : b2f(((const u16*)p)[i]);
}
// async global->LDS, 16B per lane, dest = wave-uniform base + lane*16
__device__ __forceinline__ void gload_lds16(const void* g, void* l) {
  __builtin_amdgcn_global_load_lds((const __attribute__((address_space(1))) void*)g,
                                   (__attribute__((address_space(3))) void*)l,
                                   16, 0, 0);
}

// ---- detect input dtype from batchgraphin bit patterns.
__global__ void k_detect(const u16* g, int* flag) {
  __shared__ int bad;
  if (threadIdx.x == 0) bad = 0;
  __syncthreads();
  int any = 0;
  for (int i = threadIdx.x; i < 8192; i += 256) any |= (g[i] > 0x3B00);
  if (any) atomicOr(&bad, 1);
  __syncthreads();
  if (threadIdx.x == 0) *flag = bad;   // 1 => inputs are f32
}

// ---- generic convert-to-f32
__global__ void k_cvtf(const void* src, float* dst, int n, const int* flagp) {
  int i = blockIdx.x * 256 + threadIdx.x;
  if (i < n) dst[i] = ldu(src, i, *flagp);
}

// ---- Weff = sum_e Wcat[:, e*128+k], stored j-major as bf16 hi/lo pair.
// weffHT/weffLT: [j=0..1023][k=0..127]. biasf = [b_in | b_out] f32.
__global__ void k_weff(const void* Win, const void* bin, const void* Wout, const void* bout,
                       u16* weffHT, u16* weffLT, float* biasf, const int* flagp) {
  int flag = *flagp;
  int idx = blockIdx.x * 256 + threadIdx.x;   // 131072
  int j = idx >> 7, k = idx & 127;
  float s = 0.f;
  if (j < 512) {
#pragma unroll
    for (int e = 0; e < 4; e++) s += ldu(Win, (size_t)j * 512 + e * 128 + k, flag);
  } else {
#pragma unroll
    for (int e = 0; e < 4; e++) s += ldu(Wout, (size_t)(j - 512) * 512 + e * 128 + k, flag);
  }
  u16 h = f2bf(s);
  weffHT[(size_t)j * 128 + k] = h;
  weffLT[(size_t)j * 128 + k] = f2bf(s - b2f(h));
  if (idx < 1024) biasf[idx] = (idx < 512) ? ldu(bin, idx, flag) : ldu(bout, idx - 512, flag);
}

// ---- gate weights -> bf16 hi/lo, layout [gate*128+n][k=0..383]; biases f32.
__global__ void k_wt3(const void* Wr, const void* Wz, const void* Wt,
                      const void* br, const void* bz, const void* bt,
                      u16* wt3H, u16* wt3L,
                      float* brf, float* bzf, float* btf, const int* flagp) {
  int flag = *flagp;
  int idx = blockIdx.x * 256 + threadIdx.x;   // 3*128*384 = 147456
  int g = idx / 49152, rem = idx % 49152;
  const void* W = (g == 0) ? Wr : (g == 1) ? Wz : Wt;
  float s = ldu(W, rem, flag);                // W is [128 n][384 k] row-major
  u16 h = f2bf(s);
  wt3H[(size_t)idx] = h;                      // idx == (g*128+n)*384 + k
  wt3L[(size_t)idx] = f2bf(s - b2f(h));
  if (rem < 128) {
    float bv = ldu((g == 0) ? br : (g == 1) ? bz : bt, rem, flag);
    ((g == 0) ? brf : (g == 1) ? bzf : btf)[rem] = bv;
  }
}

// ---- MFMA pre: per (b, 32-s block): Y[32,1024] = X[32,128] @ WeffT^T, hi/lo
// compensated. gpreT[gb][d][k2=s*4+e] = bf16(Y[s][gate*512+e*128+d]+bias).
__global__ __launch_bounds__(512, 2) void kg_pre_mfma(
    const u16* __restrict__ weffHT, const u16* __restrict__ weffLT,
    const float* __restrict__ biasf, const float* __restrict__ outF,
    u16* __restrict__ gpreT) {
  __shared__ __align__(16) u16 AH[32 * 128];
  __shared__ __align__(16) u16 AL[32 * 128];
  __shared__ __align__(16) u16 ybuf[32 * 1024];
  int t = threadIdx.x;
  int b = blockIdx.y;
  int s0 = blockIdx.x * 32;
  {  // stage A: 32 rows x 128 k f32 -> hi/lo bf16, XOR-swizzled
    int row = t >> 4, c8 = (t & 15) * 8;
    const float* src = outF + (((size_t)(b * 1024 + s0 + row)) << 7) + c8;
    f32x4 x0 = *(const f32x4*)src;
    f32x4 x1 = *(const f32x4*)(src + 4);
    u16x8 vh, vl;
#pragma unroll
    for (int i = 0; i < 4; i++) {
      float x = x0[i]; u16 h = f2bf(x);
      vh[i] = h; vl[i] = f2bf(x - b2f(h));
      x = x1[i]; h = f2bf(x);
      vh[i + 4] = h; vl[i + 4] = f2bf(x - b2f(h));
    }
    int bc = (c8 * 2) ^ ((row & 7) << 4);
    *(u16x8*)((char*)AH + row * 256 + bc) = vh;
    *(u16x8*)((char*)AL + row * 256 + bc) = vl;
  }
  __syncthreads();
  int lane = t & 63, w = t >> 6;
  int wm = w >> 2, wn = w & 3;        // wave tile: 16 s x 256 j
  int lr = lane & 15, lk = lane >> 4;
  int n0 = wn * 256;
  int arow = wm * 16 + lr;
  int abase_row = arow * 256;
  int aswz = (arow & 7) << 4;
  f32x4 acc[16] = {};
#pragma unroll
  for (int kk = 0; kk < 4; kk++) {
    int kb = (kk * 64 + lk * 16) ^ aswz;
    short8 ah = *(const short8*)((const char*)AH + abase_row + kb);
    short8 al = *(const short8*)((const char*)AL + abase_row + kb);
    int wko = kk * 64 + lk * 16;      // byte offset within a 256B W row
#pragma unroll
    for (int nf = 0; nf < 16; nf++) {
      int j = n0 + nf * 16 + lr;
      short8 wh = *(const short8*)((const char*)weffHT + (size_t)j * 256 + wko);
      short8 wl = *(const short8*)((const char*)weffLT + (size_t)j * 256 + wko);
      acc[nf] = __builtin_amdgcn_mfma_f32_16x16x32_bf16(ah, wh, acc[nf], 0, 0, 0);
      acc[nf] = __builtin_amdgcn_mfma_f32_16x16x32_bf16(ah, wl, acc[nf], 0, 0, 0);
      acc[nf] = __builtin_amdgcn_mfma_f32_16x16x32_bf16(al, wh, acc[nf], 0, 0, 0);
    }
  }
#pragma unroll
  for (int nf = 0; nf < 16; nf++) {
    int j = n0 + nf * 16 + lr;
    float bj = biasf[j];
#pragma unroll
    for (int i = 0; i < 4; i++) {
      int s = wm * 16 + lk * 4 + i;   // C/D: col=lane&15, row=(lane>>4)*4+reg
      ybuf[s * 1024 + j] = f2bf(acc[nf][i] + bj);
    }
  }
  __syncthreads();
#pragma unroll
  for (int p = 0; p < 8; p++) {
    int row = p * 32 + (t >> 4);
    int gate = row >> 7, d = row & 127;
    int c = (t & 15) * 8;
    u16x8 v;
#pragma unroll
    for (int i = 0; i < 8; i++) {
      int k2 = c + i;
      v[i] = ybuf[(k2 >> 2) * 1024 + gate * 512 + (k2 & 3) * 128 + d];
    }
    *(u16x8*)(gpreT + (((size_t)((gate * 8 + b) * 128 + d)) << 12) + (size_t)s0 * 4 + c) = v;
  }
}

// ---- MFMA bmm: per (gate,b,khalf): Cpart[1024,128] += graph[1024,2048]·gpre[2048,128]
// WMODE=1: fat (f32-capable; cvt + gB store in stageA_write, round-3 placement).
// WMODE=0: lean bf16-only (steps 1-4 when workspace cache is valid).
template <int WMODE>
__global__ __launch_bounds__(256, 2) void kg_bmm(
    const void* __restrict__ gin, const void* __restrict__ gout,
    u16* __restrict__ gB, int useGB, int writeStep,
    const u16* __restrict__ gpreT,
    float* __restrict__ P,
    const int* __restrict__ flagp) {
  __shared__ __align__(16) u16 bufA[2][4096];   // [64 s-rows][64 k], swizzled
  __shared__ __align__(16) u16 bufB[2][8192];   // [128 d-cols][64 k], swizzled

  int t = threadIdx.x;
  int lin0 = blockIdx.x + (blockIdx.y << 4) + (blockIdx.z << 8);
  int lin = ((lin0 & 7) << 6) + (lin0 >> 3);    // XCD chunk swizzle, 512%8==0
  int mb = lin & 15, gb = (lin >> 4) & 15, kh = lin >> 8;
  int gate = gb >> 3, b = gb & 7;
  int ms0 = mb << 6;
  int kbase = kh << 11;

  int flag = *flagp;
  int doWrite = 0, srcBF = 1;
  const void* Asrc;
  size_t abase;   // element index of A[ms0][kbase] in Asrc
  if (WMODE == 0) {
    if (flag) { Asrc = gB;                abase = (((size_t)(gb * 1024 + ms0)) << 12) + kbase; }
    else      { Asrc = gate ? gout : gin; abase = (((size_t)(b  * 1024 + ms0)) << 12) + kbase; }
  } else {
    doWrite = useGB && flag && writeStep;
    srcBF = (flag == 0);
    Asrc = gate ? gout : gin;
    abase = (((size_t)(b * 1024 + ms0)) << 12) + kbase;
  }
  size_t gwbase = (((size_t)(gb * 1024 + ms0)) << 12) + kbase;   // gB write base

  int arow = t >> 4;            // 0..15 (+16 per it)
  int acolE = (t & 15) << 2;    // elem col
  int acb = (t & 15) << 3;      // byte col
  int aswz = (arow & 7) << 4;
  int lane = t & 63, w = t >> 6;
  int wm = w >> 1, wn = w & 1;
  int lr = lane & 15, lk = lane >> 4;
  int r0 = wm * 32 + lr;
  int c0 = wn * 64 + lr;
  int fswz = (lr & 7) << 4;

  f32x4 acc[2][4] = {};
  f32x4 af[4]; u16x4 ah[4];

  auto stageA_load = [&](int st) {
    size_t kk = abase + (size_t)st * 64;
    if (WMODE == 0 || srcBF) {
      const u16* p = (const u16*)Asrc;
#pragma unroll
      for (int it = 0; it < 4; it++)
        ah[it] = *(const u16x4*)(p + kk + (size_t)(arow + it * 16) * 4096 + acolE);
    } else {
      const float* p = (const float*)Asrc;
#pragma unroll
      for (int it = 0; it < 4; it++) {
        const f32x4* a = (const f32x4*)(p + kk + (size_t)(arow + it * 16) * 4096 + acolE);
        af[it] = doWrite ? __builtin_nontemporal_load(a) : *a;
      }
    }
  };
  auto stageA_write = [&](int nb, int st) {
#pragma unroll
    for (int it = 0; it < 4; it++) {
      int row = arow + it * 16;
      u16x4 v;
      if (WMODE == 0 || srcBF) v = ah[it];
      else { v[0] = f2bf(af[it][0]); v[1] = f2bf(af[it][1]);
             v[2] = f2bf(af[it][2]); v[3] = f2bf(af[it][3]); }
      *(u16x4*)((char*)bufA[nb] + row * 128 + (acb ^ aswz)) = v;
      if (WMODE == 1 && doWrite)
        *(u16x4*)(gB + gwbase + (size_t)st * 64 + (size_t)row * 4096 + acolE) = v;
    }
  };
  auto stageB = [&](int st, int nb) {
    size_t kk = (size_t)kbase + (size_t)st * 64;
#pragma unroll
    for (int c = 0; c < 4; c++) {
      int col = (w << 5) + (c << 3) + (lane >> 3);
      int j = (lane & 7) ^ (col & 7);            // inverse swizzle on source
      const u16* g = gpreT + (((size_t)(gb * 128 + col)) << 12) + kk + (size_t)j * 8;
      u16* l = &bufB[nb][w * 2048 + c * 512];    // wave-uniform dest base
      gload_lds16(g, l);
    }
  };
  auto compute = [&](int cur) {
    const char* A = (const char*)bufA[cur];
    const char* B = (const char*)bufB[cur];
#pragma unroll
    for (int ks = 0; ks < 2; ks++) {
      int kb = (ks * 64 + lk * 16) ^ fswz;
      short8 a0 = *(const short8*)(A + r0 * 128 + kb);
      short8 a1 = *(const short8*)(A + r0 * 128 + 2048 + kb);
#pragma unroll
      for (int nf = 0; nf < 4; nf++) {
        short8 bv = *(const short8*)(B + c0 * 128 + nf * 2048 + kb);
        acc[0][nf] = __builtin_amdgcn_mfma_f32_16x16x32_bf16(a0, bv, acc[0][nf], 0, 0, 0);
        acc[1][nf] = __builtin_amdgcn_mfma_f32_16x16x32_bf16(a1, bv, acc[1][nf], 0, 0, 0);
      }
    }
  };

  stageA_load(0);
  stageB(0, 0);
  stageA_write(0, 0);
  __syncthreads();
  int cur = 0;
#pragma unroll 2
  for (int st = 0; st < 32; st++) {       // 2048 / 64
    if (st < 31) { stageA_load(st + 1); stageB(st + 1, cur ^ 1); }
    compute(cur);
    if (st < 31) stageA_write(cur ^ 1, st + 1);
    __syncthreads();
    cur ^= 1;
  }

  float* Pp = P + (((size_t)(kh * 16 + gb)) << 17);   // *1024*128
#pragma unroll
  for (int mf = 0; mf < 2; mf++) {
#pragma unroll
    for (int nf = 0; nf < 4; nf++) {
      int rowb = ms0 + wm * 32 + mf * 16 + lk * 4;
      int col = wn * 64 + nf * 16 + lr;
#pragma unroll
      for (int j = 0; j < 4; j++)
        Pp[(size_t)(rowb + j) * 128 + col] = acc[mf][nf][j];
    }
  }
}

// ---- MFMA gate tail: combine partials + r,z,t gates + GRU update, hi/lo
// compensated on both operands (3 MFMAs per product, err ~2^-18).
// Per block: 16 rows (m0=blockIdx*16), 4 waves each owning 32 cols of each gate.
__global__ __launch_bounds__(256, 2) void kg_gate_mfma(
    const float* __restrict__ P, float* __restrict__ outF,
    const u16* __restrict__ wt3H, const u16* __restrict__ wt3L,
    const float* __restrict__ brf, const float* __restrict__ bzf,
    const float* __restrict__ btf,
    const int* __restrict__ flagp, void* __restrict__ dout, int writeOut) {
  __shared__ __align__(16) u16 csH[16 * 384];   // cat hi, swizzled
  __shared__ __align__(16) u16 csL[16 * 384];   // cat lo
  __shared__ __align__(16) float outS[16 * 128];
  __shared__ __align__(16) float zs[16 * 128];
  __shared__ __align__(16) u16 rsH[16 * 128];   // r*out hi, swizzled
  __shared__ __align__(16) u16 rsL[16 * 128];
  int t = threadIdx.x;
  int m0 = blockIdx.x * 16;
  int b = m0 >> 10;
  // stage cat = [gi|go|out]: combine K-split partials, split to bf16 hi/lo
  for (int i4 = t; i4 < 1536; i4 += 256) {
    int r = i4 / 96, q = i4 % 96;
    int m = m0 + r, s = m & 1023;
    f32x4 v;
    if (q < 64) {
      int gate = q >> 5;
      size_t idx = (((size_t)(gate * 8 + b)) << 17) + ((size_t)s << 7) + ((size_t)(q & 31) << 2);
      v = *(const f32x4*)(P + idx) + *(const f32x4*)(P + ((size_t)1 << 21) + idx);
    } else {
      v = *(const f32x4*)(outF + ((size_t)m << 7) + ((q - 64) << 2));
      *(f32x4*)&outS[r * 128 + ((q - 64) << 2)] = v;
    }
    u16x4 vh, vl;
#pragma unroll
    for (int i = 0; i < 4; i++) {
      u16 h = f2bf(v[i]);
      vh[i] = h; vl[i] = f2bf(v[i] - b2f(h));
    }
    int byte = (q * 8) ^ ((r & 7) << 4);
    *(u16x4*)((char*)csH + r * 768 + byte) = vh;
    *(u16x4*)((char*)csL + r * 768 + byte) = vl;
  }
  __syncthreads();

  int lane = t & 63, w = t >> 6;
  int lr = lane & 15, lk = lane >> 4;
  int aswz = (lr & 7) << 4;
  const char* cH = (const char*)csH + lr * 768;
  const char* cL = (const char*)csL + lr * 768;
  f32x4 accR[2] = {}, accZ[2] = {}, accT[2] = {};
  for (int kc = 0; kc < 12; kc++) {
    int ab = (kc * 64 + lk * 16) ^ aswz;
    short8 aH = *(const short8*)(cH + ab);
    short8 aL = *(const short8*)(cL + ab);
    int kb = kc * 64 + lk * 16;   // byte offset within a 768B weight row
#pragma unroll
    for (int nf = 0; nf < 2; nf++) {
      int nl = w * 32 + nf * 16 + lr;          // gate-local output col
      size_t offR = (size_t)nl * 768 + kb;
      size_t offZ = (size_t)(128 + nl) * 768 + kb;
      short8 bH = *(const short8*)((const char*)wt3H + offR);
      short8 bL = *(const short8*)((const char*)wt3L + offR);
      accR[nf] = __builtin_amdgcn_mfma_f32_16x16x32_bf16(aH, bH, accR[nf], 0, 0, 0);
      accR[nf] = __builtin_amdgcn_mfma_f32_16x16x32_bf16(aH, bL, accR[nf], 0, 0, 0);
      accR[nf] = __builtin_amdgcn_mfma_f32_16x16x32_bf16(aL, bH, accR[nf], 0, 0, 0);
      bH = *(const short8*)((const char*)wt3H + offZ);
      bL = *(const short8*)((const char*)wt3L + offZ);
      accZ[nf] = __builtin_amdgcn_mfma_f32_16x16x32_bf16(aH, bH, accZ[nf], 0, 0, 0);
      accZ[nf] = __builtin_amdgcn_mfma_f32_16x16x32_bf16(aH, bL, accZ[nf], 0, 0, 0);
      accZ[nf] = __builtin_amdgcn_mfma_f32_16x16x32_bf16(aL, bH, accZ[nf], 0, 0, 0);
      if (kc < 8) {   // t-gate over k=0..255 (gi|go); 256..383 deferred to tail
        size_t offT = (size_t)(256 + nl) * 768 + kb;
        bH = *(const short8*)((const char*)wt3H + offT);
        bL = *(const short8*)((const char*)wt3L + offT);
        accT[nf] = __builtin_amdgcn_mfma_f32_16x16x32_bf16(aH, bH, accT[nf], 0, 0, 0);
        accT[nf] = __builtin_amdgcn_mfma_f32_16x16x32_bf16(aH, bL, accT[nf], 0, 0, 0);
        accT[nf] = __builtin_amdgcn_mfma_f32_16x16x32_bf16(aL, bH, accT[nf], 0, 0, 0);
      }
    }
  }
  // sigmoid; build zs (f32) and rs = hi/lo(r*out)
#pragma unroll
  for (int nf = 0; nf < 2; nf++) {
    int nl = w * 32 + nf * 16 + lr;
    float bR = brf[nl], bZ = bzf[nl];
#pragma unroll
    for (int i = 0; i < 4; i++) {
      int row = lk * 4 + i;       // C/D: col=lane&15, row=(lane>>4)*4+reg
      float rv = 1.f / (1.f + __expf(-(accR[nf][i] + bR)));
      float zv = 1.f / (1.f + __expf(-(accZ[nf][i] + bZ)));
      zs[row * 128 + nl] = zv;
      float rp = rv * outS[row * 128 + nl];
      u16 h = f2bf(rp);
      int byte = (nl * 2) ^ ((row & 7) << 4);
      *(u16*)((char*)rsH + row * 256 + byte) = h;
      *(u16*)((char*)rsL + row * 256 + byte) = f2bf(rp - b2f(h));
    }
  }
  __syncthreads();
  // t-gate tail: (r*out) @ Wt[:,256:384]
  const char* rH = (const char*)rsH + lr * 256;
  const char* rL = (const char*)rsL + lr * 256;
#pragma unroll
  for (int kc = 0; kc < 4; kc++) {
    int ab = (kc * 64 + lk * 16) ^ aswz;
    short8 aH = *(const short8*)(rH + ab);
    short8 aL = *(const short8*)(rL + ab);
    int kb = 512 + kc * 64 + lk * 16;
#pragma unroll
    for (int nf = 0; nf < 2; nf++) {
      int nl = w * 32 + nf * 16 + lr;
      size_t off = (size_t)(256 + nl) * 768 + kb;
      short8 bH = *(const short8*)((const char*)wt3H + off);
      short8 bL = *(const short8*)((const char*)wt3L + off);
      accT[nf] = __builtin_amdgcn_mfma_f32_16x16x32_bf16(aH, bH, accT[nf], 0, 0, 0);
      accT[nf] = __builtin_amdgcn_mfma_f32_16x16x32_bf16(aH, bL, accT[nf], 0, 0, 0);
      accT[nf] = __builtin_amdgcn_mfma_f32_16x16x32_bf16(aL, bH, accT[nf], 0, 0, 0);
    }
  }
  // GRU update + output
  int flag = *flagp;
#pragma unroll
  for (int nf = 0; nf < 2; nf++) {
    int nl = w * 32 + nf * 16 + lr;
    float bT = btf[nl];
#pragma unroll
    for (int i = 0; i < 4; i++) {
      int row = lk * 4 + i;
      float h = tanhf(accT[nf][i] + bT);
      float z = zs[row * 128 + nl];
      float ov = outS[row * 128 + nl];
      float res = (1.f - z) * ov + z * h;
      size_t o = (size_t)(m0 + row) * 128 + nl;
      outF[o] = res;
      if (writeOut) {
        if (flag) ((float*)dout)[o] = res;
        else      ((u16*)dout)[o] = f2bf(res);
      }
    }
  }
}

extern "C" void kernel_launch(void* const* d_in, const int* in_sizes, int n_in,
                              void* d_out, int out_size, void* d_ws, size_t ws_size,
                              hipStream_t stream) {
  const void* X    = d_in[0];
  const void* Gin  = d_in[1];
  const void* Gout = d_in[2];
  const void* Win  = d_in[3];
  const void* bin  = d_in[4];
  const void* Wout = d_in[5];
  const void* bout = d_in[6];
  const void* Wr   = d_in[7];
  const void* br   = d_in[8];
  const void* Wz   = d_in[9];
  const void* bz   = d_in[10];
  const void* Wt   = d_in[11];
  const void* bt   = d_in[12];

  char* w = (char*)d_ws;
  auto alloc = [&](size_t n) { char* p = w; w += (n + 255) & ~(size_t)255; return p; };
  int*   flag    = (int*)alloc(4);
  u16*   weffHT  = (u16*)alloc((size_t)1024 * 128 * 2);              // 256 KB
  u16*   weffLT  = (u16*)alloc((size_t)1024 * 128 * 2);              // 256 KB
  float* biasf   = (float*)alloc(1024 * 4);
  u16*   wt3H    = (u16*)alloc((size_t)3 * 128 * 384 * 2);           // 288 KB
  u16*   wt3L    = (u16*)alloc((size_t)3 * 128 * 384 * 2);           // 288 KB
  float* brf     = (float*)alloc(128 * 4);
  float* bzf     = (float*)alloc(128 * 4);
  float* btf     = (float*)alloc(128 * 4);
  float* outF    = (float*)alloc((size_t)8192 * 128 * 4);            // 4 MB
  u16*   gpreT   = (u16*)alloc((size_t)16 * 128 * 4096 * 2);         // 16 MB bf16 [gb][d][k]
  float* partial = (float*)alloc((size_t)2 * 16 * 1024 * 128 * 4);   // 16 MB K-split partials
  u16*   gB      = (u16*)alloc((size_t)2 * 8 * 1024 * 4096 * 2);     // 128 MB bf16 graph
  int wsok = ((size_t)(w - (char*)d_ws) <= ws_size) ? 1 : 0;
  (void)in_sizes; (void)n_in; (void)out_size;

  k_detect<<<1, 256, 0, stream>>>((const u16*)Gin, flag);
  k_weff<<<512, 256, 0, stream>>>(Win, bin, Wout, bout, weffHT, weffLT, biasf, flag);
  k_wt3<<<576, 256, 0, stream>>>(Wr, Wz, Wt, br, bz, bt, wt3H, wt3L, brf, bzf, btf, flag);
  k_cvtf<<<4096, 256, 0, stream>>>(X, outF, 1048576, flag);

  for (int step = 0; step < 5; step++) {
    kg_pre_mfma<<<dim3(32, 8), 512, 0, stream>>>(weffHT, weffLT, biasf, outF, gpreT);
    if (step == 0 || !wsok)
      kg_bmm<1><<<dim3(16, 16, 2), 256, 0, stream>>>(Gin, Gout, gB, wsok,
                                                     (step == 0) ? 1 : 0,
                                                     gpreT, partial, flag);
    else
      kg_bmm<0><<<dim3(16, 16, 2), 256, 0, stream>>>(Gin, Gout, gB, wsok, 0,
                                                     gpreT, partial, flag);
    kg_gate_mfma<<<512, 256, 0, stream>>>(partial, outF, wt3H, wt3L, brf, bzf, btf,
                                          flag, d_out, (step == 4) ? 1 : 0);
  }
}

// Round 8
// 885.088 us; speedup vs baseline: 1.1937x; 1.0082x over previous
//
#include <hip/hip_runtime.h>
#include <cstdint>
#include <cstddef>

// Round 11: fuse pre into gate. The gate block (16 rows x 128 d) holds res in
// registers - exactly pre's A-matrix (M=16,K=128,N=1024). Appending pre's
// hi/lo MFMA to the gate kernel kills 4 standalone pre dispatches + the
// outF->pre round-trip. Standalone pre only for step 0. LDS phases overlaid
// in one 40KB arena (cs/rs -> ybuf, outS -> resH/L), zs -> registers.
// kg_bmm untouched (note: launch_bounds occupancy bump is a no-op at grid=2
// blocks/CU; bmm re-tiling deferred to next round).
// B=8, SL=1024, D=128, E=4, STEPS=5.

typedef unsigned short u16;
typedef unsigned int u32;
typedef float f32x4 __attribute__((ext_vector_type(4)));
typedef short short8 __attribute__((ext_vector_type(8)));   // 8 bf16 (4 VGPRs)
typedef u16 u16x4 __attribute__((ext_vector_type(4)));
typedef u16 u16x8 __attribute__((ext_vector_type(8)));

__device__ __forceinline__ float b2f(u16 h) {
  union { u32 u; float f; } v; v.u = ((u32)h) << 16; return v.f;
}
__device__ __forceinline__ u16 f2bf(float f) {
  union { float f; u32 u; } v; v.f = f;
  u32 r = (v.u + 0x7fffu + ((v.u >> 16) & 1u)) >> 16;
  return (u16)r;
}
__device__ __forceinline__ float ldu(const void* p, size_t i, int flag) {
  return flag ? ((const float*)p)[i] : b2f(((const u16*)p)[i]);
}
// async global->LDS, 16B per lane, dest = wave-uniform base + lane*16
__device__ __forceinline__ void gload_lds16(const void* g, void* l) {
  __builtin_amdgcn_global_load_lds((const __attribute__((address_space(1))) void*)g,
                                   (__attribute__((address_space(3))) void*)l,
                                   16, 0, 0);
}

// ---- detect input dtype from batchgraphin bit patterns.
__global__ void k_detect(const u16* g, int* flag) {
  __shared__ int bad;
  if (threadIdx.x == 0) bad = 0;
  __syncthreads();
  int any = 0;
  for (int i = threadIdx.x; i < 8192; i += 256) any |= (g[i] > 0x3B00);
  if (any) atomicOr(&bad, 1);
  __syncthreads();
  if (threadIdx.x == 0) *flag = bad;   // 1 => inputs are f32
}

// ---- generic convert-to-f32
__global__ void k_cvtf(const void* src, float* dst, int n, const int* flagp) {
  int i = blockIdx.x * 256 + threadIdx.x;
  if (i < n) dst[i] = ldu(src, i, *flagp);
}

// ---- Weff = sum_e Wcat[:, e*128+k], stored j-major as bf16 hi/lo pair.
// weffHT/weffLT: [j=0..1023][k=0..127]. biasf = [b_in | b_out] f32.
__global__ void k_weff(const void* Win, const void* bin, const void* Wout, const void* bout,
                       u16* weffHT, u16* weffLT, float* biasf, const int* flagp) {
  int flag = *flagp;
  int idx = blockIdx.x * 256 + threadIdx.x;   // 131072
  int j = idx >> 7, k = idx & 127;
  float s = 0.f;
  if (j < 512) {
#pragma unroll
    for (int e = 0; e < 4; e++) s += ldu(Win, (size_t)j * 512 + e * 128 + k, flag);
  } else {
#pragma unroll
    for (int e = 0; e < 4; e++) s += ldu(Wout, (size_t)(j - 512) * 512 + e * 128 + k, flag);
  }
  u16 h = f2bf(s);
  weffHT[(size_t)j * 128 + k] = h;
  weffLT[(size_t)j * 128 + k] = f2bf(s - b2f(h));
  if (idx < 1024) biasf[idx] = (idx < 512) ? ldu(bin, idx, flag) : ldu(bout, idx - 512, flag);
}

// ---- gate weights -> bf16 hi/lo, layout [gate*128+n][k=0..383]; biases f32.
__global__ void k_wt3(const void* Wr, const void* Wz, const void* Wt,
                      const void* br, const void* bz, const void* bt,
                      u16* wt3H, u16* wt3L,
                      float* brf, float* bzf, float* btf, const int* flagp) {
  int flag = *flagp;
  int idx = blockIdx.x * 256 + threadIdx.x;   // 3*128*384 = 147456
  int g = idx / 49152, rem = idx % 49152;
  const void* W = (g == 0) ? Wr : (g == 1) ? Wz : Wt;
  float s = ldu(W, rem, flag);                // W is [128 n][384 k] row-major
  u16 h = f2bf(s);
  wt3H[(size_t)idx] = h;                      // idx == (g*128+n)*384 + k
  wt3L[(size_t)idx] = f2bf(s - b2f(h));
  if (rem < 128) {
    float bv = ldu((g == 0) ? br : (g == 1) ? bz : bt, rem, flag);
    ((g == 0) ? brf : (g == 1) ? bzf : btf)[rem] = bv;
  }
}

// ---- MFMA pre (standalone, step 0 only): per (b, 32-s block):
// Y[32,1024] = X[32,128] @ WeffT^T, hi/lo compensated.
__global__ __launch_bounds__(512, 2) void kg_pre_mfma(
    const u16* __restrict__ weffHT, const u16* __restrict__ weffLT,
    const float* __restrict__ biasf, const float* __restrict__ outF,
    u16* __restrict__ gpreT) {
  __shared__ __align__(16) u16 AH[32 * 128];
  __shared__ __align__(16) u16 AL[32 * 128];
  __shared__ __align__(16) u16 ybuf[32 * 1024];
  int t = threadIdx.x;
  int b = blockIdx.y;
  int s0 = blockIdx.x * 32;
  {
    int row = t >> 4, c8 = (t & 15) * 8;
    const float* src = outF + (((size_t)(b * 1024 + s0 + row)) << 7) + c8;
    f32x4 x0 = *(const f32x4*)src;
    f32x4 x1 = *(const f32x4*)(src + 4);
    u16x8 vh, vl;
#pragma unroll
    for (int i = 0; i < 4; i++) {
      float x = x0[i]; u16 h = f2bf(x);
      vh[i] = h; vl[i] = f2bf(x - b2f(h));
      x = x1[i]; h = f2bf(x);
      vh[i + 4] = h; vl[i + 4] = f2bf(x - b2f(h));
    }
    int bc = (c8 * 2) ^ ((row & 7) << 4);
    *(u16x8*)((char*)AH + row * 256 + bc) = vh;
    *(u16x8*)((char*)AL + row * 256 + bc) = vl;
  }
  __syncthreads();
  int lane = t & 63, w = t >> 6;
  int wm = w >> 2, wn = w & 3;
  int lr = lane & 15, lk = lane >> 4;
  int n0 = wn * 256;
  int arow = wm * 16 + lr;
  int abase_row = arow * 256;
  int aswz = (arow & 7) << 4;
  f32x4 acc[16] = {};
#pragma unroll
  for (int kk = 0; kk < 4; kk++) {
    int kb = (kk * 64 + lk * 16) ^ aswz;
    short8 ah = *(const short8*)((const char*)AH + abase_row + kb);
    short8 al = *(const short8*)((const char*)AL + abase_row + kb);
    int wko = kk * 64 + lk * 16;
#pragma unroll
    for (int nf = 0; nf < 16; nf++) {
      int j = n0 + nf * 16 + lr;
      short8 wh = *(const short8*)((const char*)weffHT + (size_t)j * 256 + wko);
      short8 wl = *(const short8*)((const char*)weffLT + (size_t)j * 256 + wko);
      acc[nf] = __builtin_amdgcn_mfma_f32_16x16x32_bf16(ah, wh, acc[nf], 0, 0, 0);
      acc[nf] = __builtin_amdgcn_mfma_f32_16x16x32_bf16(ah, wl, acc[nf], 0, 0, 0);
      acc[nf] = __builtin_amdgcn_mfma_f32_16x16x32_bf16(al, wh, acc[nf], 0, 0, 0);
    }
  }
#pragma unroll
  for (int nf = 0; nf < 16; nf++) {
    int j = n0 + nf * 16 + lr;
    float bj = biasf[j];
#pragma unroll
    for (int i = 0; i < 4; i++) {
      int s = wm * 16 + lk * 4 + i;
      ybuf[s * 1024 + j] = f2bf(acc[nf][i] + bj);
    }
  }
  __syncthreads();
#pragma unroll
  for (int p = 0; p < 8; p++) {
    int row = p * 32 + (t >> 4);
    int gate = row >> 7, d = row & 127;
    int c = (t & 15) * 8;
    u16x8 v;
#pragma unroll
    for (int i = 0; i < 8; i++) {
      int k2 = c + i;
      v[i] = ybuf[(k2 >> 2) * 1024 + gate * 512 + (k2 & 3) * 128 + d];
    }
    *(u16x8*)(gpreT + (((size_t)((gate * 8 + b) * 128 + d)) << 12) + (size_t)s0 * 4 + c) = v;
  }
}

// ---- MFMA bmm (unchanged from passing round-10)
template <int WMODE>
__global__ __launch_bounds__(256, 2) void kg_bmm(
    const void* __restrict__ gin, const void* __restrict__ gout,
    u16* __restrict__ gB, int useGB, int writeStep,
    const u16* __restrict__ gpreT,
    float* __restrict__ P,
    const int* __restrict__ flagp) {
  __shared__ __align__(16) u16 bufA[2][4096];
  __shared__ __align__(16) u16 bufB[2][8192];

  int t = threadIdx.x;
  int lin0 = blockIdx.x + (blockIdx.y << 4) + (blockIdx.z << 8);
  int lin = ((lin0 & 7) << 6) + (lin0 >> 3);    // XCD chunk swizzle, 512%8==0
  int mb = lin & 15, gb = (lin >> 4) & 15, kh = lin >> 8;
  int gate = gb >> 3, b = gb & 7;
  int ms0 = mb << 6;
  int kbase = kh << 11;

  int flag = *flagp;
  int doWrite = 0, srcBF = 1;
  const void* Asrc;
  size_t abase;
  if (WMODE == 0) {
    if (flag) { Asrc = gB;                abase = (((size_t)(gb * 1024 + ms0)) << 12) + kbase; }
    else      { Asrc = gate ? gout : gin; abase = (((size_t)(b  * 1024 + ms0)) << 12) + kbase; }
  } else {
    doWrite = useGB && flag && writeStep;
    srcBF = (flag == 0);
    Asrc = gate ? gout : gin;
    abase = (((size_t)(b * 1024 + ms0)) << 12) + kbase;
  }
  size_t gwbase = (((size_t)(gb * 1024 + ms0)) << 12) + kbase;

  int arow = t >> 4;
  int acolE = (t & 15) << 2;
  int acb = (t & 15) << 3;
  int aswz = (arow & 7) << 4;
  int lane = t & 63, w = t >> 6;
  int wm = w >> 1, wn = w & 1;
  int lr = lane & 15, lk = lane >> 4;
  int r0 = wm * 32 + lr;
  int c0 = wn * 64 + lr;
  int fswz = (lr & 7) << 4;

  f32x4 acc[2][4] = {};
  f32x4 af[4]; u16x4 ah[4];

  auto stageA_load = [&](int st) {
    size_t kk = abase + (size_t)st * 64;
    if (WMODE == 0 || srcBF) {
      const u16* p = (const u16*)Asrc;
#pragma unroll
      for (int it = 0; it < 4; it++)
        ah[it] = *(const u16x4*)(p + kk + (size_t)(arow + it * 16) * 4096 + acolE);
    } else {
      const float* p = (const float*)Asrc;
#pragma unroll
      for (int it = 0; it < 4; it++) {
        const f32x4* a = (const f32x4*)(p + kk + (size_t)(arow + it * 16) * 4096 + acolE);
        af[it] = doWrite ? __builtin_nontemporal_load(a) : *a;
      }
    }
  };
  auto stageA_write = [&](int nb, int st) {
#pragma unroll
    for (int it = 0; it < 4; it++) {
      int row = arow + it * 16;
      u16x4 v;
      if (WMODE == 0 || srcBF) v = ah[it];
      else { v[0] = f2bf(af[it][0]); v[1] = f2bf(af[it][1]);
             v[2] = f2bf(af[it][2]); v[3] = f2bf(af[it][3]); }
      *(u16x4*)((char*)bufA[nb] + row * 128 + (acb ^ aswz)) = v;
      if (WMODE == 1 && doWrite)
        *(u16x4*)(gB + gwbase + (size_t)st * 64 + (size_t)row * 4096 + acolE) = v;
    }
  };
  auto stageB = [&](int st, int nb) {
    size_t kk = (size_t)kbase + (size_t)st * 64;
#pragma unroll
    for (int c = 0; c < 4; c++) {
      int col = (w << 5) + (c << 3) + (lane >> 3);
      int j = (lane & 7) ^ (col & 7);
      const u16* g = gpreT + (((size_t)(gb * 128 + col)) << 12) + kk + (size_t)j * 8;
      u16* l = &bufB[nb][w * 2048 + c * 512];
      gload_lds16(g, l);
    }
  };
  auto compute = [&](int cur) {
    const char* A = (const char*)bufA[cur];
    const char* B = (const char*)bufB[cur];
#pragma unroll
    for (int ks = 0; ks < 2; ks++) {
      int kb = (ks * 64 + lk * 16) ^ fswz;
      short8 a0 = *(const short8*)(A + r0 * 128 + kb);
      short8 a1 = *(const short8*)(A + r0 * 128 + 2048 + kb);
#pragma unroll
      for (int nf = 0; nf < 4; nf++) {
        short8 bv = *(const short8*)(B + c0 * 128 + nf * 2048 + kb);
        acc[0][nf] = __builtin_amdgcn_mfma_f32_16x16x32_bf16(a0, bv, acc[0][nf], 0, 0, 0);
        acc[1][nf] = __builtin_amdgcn_mfma_f32_16x16x32_bf16(a1, bv, acc[1][nf], 0, 0, 0);
      }
    }
  };

  stageA_load(0);
  stageB(0, 0);
  stageA_write(0, 0);
  __syncthreads();
  int cur = 0;
#pragma unroll 2
  for (int st = 0; st < 32; st++) {
    if (st < 31) { stageA_load(st + 1); stageB(st + 1, cur ^ 1); }
    compute(cur);
    if (st < 31) stageA_write(cur ^ 1, st + 1);
    __syncthreads();
    cur ^= 1;
  }

  float* Pp = P + (((size_t)(kh * 16 + gb)) << 17);
#pragma unroll
  for (int mf = 0; mf < 2; mf++) {
#pragma unroll
    for (int nf = 0; nf < 4; nf++) {
      int rowb = ms0 + wm * 32 + mf * 16 + lk * 4;
      int col = wn * 64 + nf * 16 + lr;
#pragma unroll
      for (int j = 0; j < 4; j++)
        Pp[(size_t)(rowb + j) * 128 + col] = acc[mf][nf][j];
    }
  }
}

// ---- fused gate (+ pre for next step when DOPRE): combine partials, r/z/t
// gates hi/lo MFMA, GRU update, then (DOPRE) res @ WeffT^T -> gpreT.
// LDS arena 40KB, phases overlaid: {csH,csL,rsH,rsL}->ybuf ; outS->resH/L.
template <int DOPRE>
__global__ __launch_bounds__(256, 2) void kg_gate_mfma(
    const float* __restrict__ P, float* __restrict__ outF,
    const u16* __restrict__ wt3H, const u16* __restrict__ wt3L,
    const u16* __restrict__ weffHT, const u16* __restrict__ weffLT,
    const float* __restrict__ brf, const float* __restrict__ bzf,
    const float* __restrict__ btf, const float* __restrict__ biasf,
    u16* __restrict__ gpreT,
    const int* __restrict__ flagp, void* __restrict__ dout, int writeOut) {
  __shared__ __align__(16) char smem[40960];
  u16* csH   = (u16*)(smem);             // 12288 B  [16 rows x 384] swizzled
  u16* csL   = (u16*)(smem + 12288);     // 12288
  u16* rsH   = (u16*)(smem + 24576);     // 4096     [16 x 128] swizzled
  u16* rsL   = (u16*)(smem + 28672);     // 4096
  float* outS = (float*)(smem + 32768);  // 8192
  // pre-phase aliases (after GRU, behind barriers):
  u16* ybuf  = (u16*)(smem);             // 32768    [16 s x 1024 j]
  u16* resH  = (u16*)(smem + 32768);     // 4096     [16 x 128] swizzled
  u16* resL  = (u16*)(smem + 36864);     // 4096

  int t = threadIdx.x;
  int m0 = blockIdx.x * 16;
  int b = m0 >> 10;
  // stage cat = [gi|go|out]: combine K-split partials, split to bf16 hi/lo
  for (int i4 = t; i4 < 1536; i4 += 256) {
    int r = i4 / 96, q = i4 % 96;
    int m = m0 + r, s = m & 1023;
    f32x4 v;
    if (q < 64) {
      int gate = q >> 5;
      size_t idx = (((size_t)(gate * 8 + b)) << 17) + ((size_t)s << 7) + ((size_t)(q & 31) << 2);
      v = *(const f32x4*)(P + idx) + *(const f32x4*)(P + ((size_t)1 << 21) + idx);
    } else {
      v = *(const f32x4*)(outF + ((size_t)m << 7) + ((q - 64) << 2));
      *(f32x4*)&outS[r * 128 + ((q - 64) << 2)] = v;
    }
    u16x4 vh, vl;
#pragma unroll
    for (int i = 0; i < 4; i++) {
      u16 h = f2bf(v[i]);
      vh[i] = h; vl[i] = f2bf(v[i] - b2f(h));
    }
    int byte = (q * 8) ^ ((r & 7) << 4);
    *(u16x4*)((char*)csH + r * 768 + byte) = vh;
    *(u16x4*)((char*)csL + r * 768 + byte) = vl;
  }
  __syncthreads();

  int lane = t & 63, w = t >> 6;
  int lr = lane & 15, lk = lane >> 4;
  int aswz = (lr & 7) << 4;
  const char* cH = (const char*)csH + lr * 768;
  const char* cL = (const char*)csL + lr * 768;
  f32x4 accR[2] = {}, accZ[2] = {}, accT[2] = {};
  for (int kc = 0; kc < 12; kc++) {
    int ab = (kc * 64 + lk * 16) ^ aswz;
    short8 aH = *(const short8*)(cH + ab);
    short8 aL = *(const short8*)(cL + ab);
    int kb = kc * 64 + lk * 16;
#pragma unroll
    for (int nf = 0; nf < 2; nf++) {
      int nl = w * 32 + nf * 16 + lr;
      size_t offR = (size_t)nl * 768 + kb;
      size_t offZ = (size_t)(128 + nl) * 768 + kb;
      short8 bH = *(const short8*)((const char*)wt3H + offR);
      short8 bL = *(const short8*)((const char*)wt3L + offR);
      accR[nf] = __builtin_amdgcn_mfma_f32_16x16x32_bf16(aH, bH, accR[nf], 0, 0, 0);
      accR[nf] = __builtin_amdgcn_mfma_f32_16x16x32_bf16(aH, bL, accR[nf], 0, 0, 0);
      accR[nf] = __builtin_amdgcn_mfma_f32_16x16x32_bf16(aL, bH, accR[nf], 0, 0, 0);
      bH = *(const short8*)((const char*)wt3H + offZ);
      bL = *(const short8*)((const char*)wt3L + offZ);
      accZ[nf] = __builtin_amdgcn_mfma_f32_16x16x32_bf16(aH, bH, accZ[nf], 0, 0, 0);
      accZ[nf] = __builtin_amdgcn_mfma_f32_16x16x32_bf16(aH, bL, accZ[nf], 0, 0, 0);
      accZ[nf] = __builtin_amdgcn_mfma_f32_16x16x32_bf16(aL, bH, accZ[nf], 0, 0, 0);
      if (kc < 8) {
        size_t offT = (size_t)(256 + nl) * 768 + kb;
        bH = *(const short8*)((const char*)wt3H + offT);
        bL = *(const short8*)((const char*)wt3L + offT);
        accT[nf] = __builtin_amdgcn_mfma_f32_16x16x32_bf16(aH, bH, accT[nf], 0, 0, 0);
        accT[nf] = __builtin_amdgcn_mfma_f32_16x16x32_bf16(aH, bL, accT[nf], 0, 0, 0);
        accT[nf] = __builtin_amdgcn_mfma_f32_16x16x32_bf16(aL, bH, accT[nf], 0, 0, 0);
      }
    }
  }
  // sigmoid; z in registers (same-thread consumer); rs = hi/lo(r*out)
  float zreg[2][4];
#pragma unroll
  for (int nf = 0; nf < 2; nf++) {
    int nl = w * 32 + nf * 16 + lr;
    float bR = brf[nl], bZ = bzf[nl];
#pragma unroll
    for (int i = 0; i < 4; i++) {
      int row = lk * 4 + i;
      float rv = 1.f / (1.f + __expf(-(accR[nf][i] + bR)));
      zreg[nf][i] = 1.f / (1.f + __expf(-(accZ[nf][i] + bZ)));
      float rp = rv * outS[row * 128 + nl];
      u16 h = f2bf(rp);
      int byte = (nl * 2) ^ ((row & 7) << 4);
      *(u16*)((char*)rsH + row * 256 + byte) = h;
      *(u16*)((char*)rsL + row * 256 + byte) = f2bf(rp - b2f(h));
    }
  }
  __syncthreads();
  // t-gate tail: (r*out) @ Wt[:,256:384]
  const char* rH = (const char*)rsH + lr * 256;
  const char* rL = (const char*)rsL + lr * 256;
#pragma unroll
  for (int kc = 0; kc < 4; kc++) {
    int ab = (kc * 64 + lk * 16) ^ aswz;
    short8 aH = *(const short8*)(rH + ab);
    short8 aL = *(const short8*)(rL + ab);
    int kb = 512 + kc * 64 + lk * 16;
#pragma unroll
    for (int nf = 0; nf < 2; nf++) {
      int nl = w * 32 + nf * 16 + lr;
      size_t off = (size_t)(256 + nl) * 768 + kb;
      short8 bH = *(const short8*)((const char*)wt3H + off);
      short8 bL = *(const short8*)((const char*)wt3L + off);
      accT[nf] = __builtin_amdgcn_mfma_f32_16x16x32_bf16(aH, bH, accT[nf], 0, 0, 0);
      accT[nf] = __builtin_amdgcn_mfma_f32_16x16x32_bf16(aH, bL, accT[nf], 0, 0, 0);
      accT[nf] = __builtin_amdgcn_mfma_f32_16x16x32_bf16(aL, bH, accT[nf], 0, 0, 0);
    }
  }
  // GRU update + output; keep res in registers for the fused pre
  int flag = *flagp;
  float resv[2][4];
#pragma unroll
  for (int nf = 0; nf < 2; nf++) {
    int nl = w * 32 + nf * 16 + lr;
    float bT = btf[nl];
#pragma unroll
    for (int i = 0; i < 4; i++) {
      int row = lk * 4 + i;
      float h = tanhf(accT[nf][i] + bT);
      float z = zreg[nf][i];
      float ov = outS[row * 128 + nl];
      float res = (1.f - z) * ov + z * h;
      resv[nf][i] = res;
      size_t o = (size_t)(m0 + row) * 128 + nl;
      outF[o] = res;
      if (writeOut) {
        if (flag) ((float*)dout)[o] = res;
        else      ((u16*)dout)[o] = f2bf(res);
      }
    }
  }
  if (DOPRE) {
    __syncthreads();    // all reads of outS/cs/rs done -> safe to overlay
    // res -> hi/lo swizzled LDS (A-matrix, 16 rows x 128 k)
#pragma unroll
    for (int nf = 0; nf < 2; nf++) {
      int nl = w * 32 + nf * 16 + lr;
#pragma unroll
      for (int i = 0; i < 4; i++) {
        int row = lk * 4 + i;
        float x = resv[nf][i];
        u16 h = f2bf(x);
        int byte = (nl * 2) ^ ((row & 7) << 4);
        *(u16*)((char*)resH + row * 256 + byte) = h;
        *(u16*)((char*)resL + row * 256 + byte) = f2bf(x - b2f(h));
      }
    }
    __syncthreads();
    // pre MFMA: wave w owns j in [w*256, w*256+256); M=16, K=128
    f32x4 pacc[16] = {};
#pragma unroll
    for (int kk = 0; kk < 4; kk++) {
      int kb = (kk * 64 + lk * 16) ^ aswz;
      short8 ah = *(const short8*)((const char*)resH + lr * 256 + kb);
      short8 al = *(const short8*)((const char*)resL + lr * 256 + kb);
      int wko = kk * 64 + lk * 16;
#pragma unroll
      for (int nf = 0; nf < 16; nf++) {
        int j = w * 256 + nf * 16 + lr;
        short8 wh = *(const short8*)((const char*)weffHT + (size_t)j * 256 + wko);
        short8 wl = *(const short8*)((const char*)weffLT + (size_t)j * 256 + wko);
        pacc[nf] = __builtin_amdgcn_mfma_f32_16x16x32_bf16(ah, wh, pacc[nf], 0, 0, 0);
        pacc[nf] = __builtin_amdgcn_mfma_f32_16x16x32_bf16(ah, wl, pacc[nf], 0, 0, 0);
        pacc[nf] = __builtin_amdgcn_mfma_f32_16x16x32_bf16(al, wh, pacc[nf], 0, 0, 0);
      }
    }
    // +bias, round, transpose via ybuf
#pragma unroll
    for (int nf = 0; nf < 16; nf++) {
      int j = w * 256 + nf * 16 + lr;
      float bj = biasf[j];
#pragma unroll
      for (int i = 0; i < 4; i++) {
        int s = lk * 4 + i;
        ybuf[s * 1024 + j] = f2bf(pacc[nf][i] + bj);
      }
    }
    __syncthreads();
    // write gpreT: 256 rows (gate*128+d), 64 contiguous k2 each
    {
      int row = t;
      int gate = row >> 7, d = row & 127;
      int sbase = (m0 & 1023) * 4;
      u16* op = gpreT + (((size_t)((gate * 8 + b) * 128 + d)) << 12) + sbase;
#pragma unroll
      for (int p = 0; p < 8; p++) {
        u16x8 v;
#pragma unroll
        for (int i = 0; i < 8; i++) {
          int k2 = p * 8 + i;
          v[i] = ybuf[(k2 >> 2) * 1024 + gate * 512 + (k2 & 3) * 128 + d];
        }
        *(u16x8*)(op + p * 8) = v;
      }
    }
  }
}

extern "C" void kernel_launch(void* const* d_in, const int* in_sizes, int n_in,
                              void* d_out, int out_size, void* d_ws, size_t ws_size,
                              hipStream_t stream) {
  const void* X    = d_in[0];
  const void* Gin  = d_in[1];
  const void* Gout = d_in[2];
  const void* Win  = d_in[3];
  const void* bin  = d_in[4];
  const void* Wout = d_in[5];
  const void* bout = d_in[6];
  const void* Wr   = d_in[7];
  const void* br   = d_in[8];
  const void* Wz   = d_in[9];
  const void* bz   = d_in[10];
  const void* Wt   = d_in[11];
  const void* bt   = d_in[12];

  char* w = (char*)d_ws;
  auto alloc = [&](size_t n) { char* p = w; w += (n + 255) & ~(size_t)255; return p; };
  int*   flag    = (int*)alloc(4);
  u16*   weffHT  = (u16*)alloc((size_t)1024 * 128 * 2);              // 256 KB
  u16*   weffLT  = (u16*)alloc((size_t)1024 * 128 * 2);              // 256 KB
  float* biasf   = (float*)alloc(1024 * 4);
  u16*   wt3H    = (u16*)alloc((size_t)3 * 128 * 384 * 2);           // 288 KB
  u16*   wt3L    = (u16*)alloc((size_t)3 * 128 * 384 * 2);           // 288 KB
  float* brf     = (float*)alloc(128 * 4);
  float* bzf     = (float*)alloc(128 * 4);
  float* btf     = (float*)alloc(128 * 4);
  float* outF    = (float*)alloc((size_t)8192 * 128 * 4);            // 4 MB
  u16*   gpreT   = (u16*)alloc((size_t)16 * 128 * 4096 * 2);         // 16 MB bf16 [gb][d][k]
  float* partial = (float*)alloc((size_t)2 * 16 * 1024 * 128 * 4);   // 16 MB K-split partials
  u16*   gB      = (u16*)alloc((size_t)2 * 8 * 1024 * 4096 * 2);     // 128 MB bf16 graph
  int wsok = ((size_t)(w - (char*)d_ws) <= ws_size) ? 1 : 0;
  (void)in_sizes; (void)n_in; (void)out_size;

  k_detect<<<1, 256, 0, stream>>>((const u16*)Gin, flag);
  k_weff<<<512, 256, 0, stream>>>(Win, bin, Wout, bout, weffHT, weffLT, biasf, flag);
  k_wt3<<<576, 256, 0, stream>>>(Wr, Wz, Wt, br, bz, bt, wt3H, wt3L, brf, bzf, btf, flag);
  k_cvtf<<<4096, 256, 0, stream>>>(X, outF, 1048576, flag);

  // step-0 pre (standalone); later steps get gpreT from the fused gate
  kg_pre_mfma<<<dim3(32, 8), 512, 0, stream>>>(weffHT, weffLT, biasf, outF, gpreT);
  for (int step = 0; step < 5; step++) {
    if (step == 0 || !wsok)
      kg_bmm<1><<<dim3(16, 16, 2), 256, 0, stream>>>(Gin, Gout, gB, wsok,
                                                     (step == 0) ? 1 : 0,
                                                     gpreT, partial, flag);
    else
      kg_bmm<0><<<dim3(16, 16, 2), 256, 0, stream>>>(Gin, Gout, gB, wsok, 0,
                                                     gpreT, partial, flag);
    if (step < 4)
      kg_gate_mfma<1><<<512, 256, 0, stream>>>(partial, outF, wt3H, wt3L,
                                               weffHT, weffLT, brf, bzf, btf, biasf,
                                               gpreT, flag, d_out, 0);
    else
      kg_gate_mfma<0><<<512, 256, 0, stream>>>(partial, outF, wt3H, wt3L,
                                               weffHT, weffLT, brf, bzf, btf, biasf,
                                               gpreT, flag, d_out, 1);
  }
}